// Round 19
// baseline (189.138 us; speedup 1.0000x reference)
//
#include <hip/hip_runtime.h>
#include <cstdint>

// AGMBrain: B=16384, INPUT_DIM=256, N=32 neurons, D=128, 3 steps.
// Round 19: r18 with NBATCH 14->15 (LDS 162064 <= 163840).
//   r18 counters: latency-bound (73% stall), no pipe saturated; blocks
//   stream asynchronously so time ~ nblk*T/256 with T unchanged ->
//   15 batches/block = 6.7% fewer blocks (1093 vs 1171) at same T.
//   Wave map: w<15 owns batch w; wave 15 does t==2 part1 (i=31);
//   part1 2 i-rows/wave; fused out 16 cols/wave. Numerics identical ->
//   absmax must stay exactly 1.099512e12.
//   pipeline: agm_conv -> agm_xt -> agm_main   (ws 4.65MB layout unchanged)

#define BTOT 16384
#define NBATCH 15
#define ROWB 272                 // bytes per state row (128 f16 + 8 pad)
#define STB  8720                // bytes per batch (32*272 + 16 pad)
#define ST(b) ((b) * STB)
#define SC_BASE 130800           // 15*8720
#define SC_BS 2080               // 2048 + 32B pad (r16: spreads batch banks)
#define SC(b) (SC_BASE + (b) * SC_BS)  // scores S[i][j] f16, 64B/row; o31 at t==2
#define SIGF_OFF 162000          // 15 ints
#define LDS_TOTAL 162064         // <= 163840, 1 block/CU

#define WS_EH    0
#define WS_WINT  262144
#define WS_WRECT 327680
#define WS_NSMX  393216
#define WS_NSMN  393728
#define WS_XT    394240
#define WS_NEED  4654080

typedef _Float16 f16;
typedef _Float16 f16x8 __attribute__((ext_vector_type(8)));
typedef float f32x4 __attribute__((ext_vector_type(4)));
typedef unsigned int u32x4 __attribute__((ext_vector_type(4)));
typedef unsigned int u32x2 __attribute__((ext_vector_type(2)));

union H8 { u32x4 u; f16x8 h; };
union H4 { u32x2 u; f16 h[4]; };

__device__ __forceinline__ float exp2i(int e) {      // 2^e, e in [-126,127]
    return __uint_as_float((unsigned)(e + 127) << 23);
}
__device__ __forceinline__ int flog2(float m) {      // floor(log2 m), m>0 normal
    return (int)((__float_as_uint(m) >> 23) & 0xFF) - 127;
}

// ---------------- conv: edge->f16(diag0), W_inT, W_recT, ns col extremes ----
__global__ void agm_conv(const float* __restrict__ edge, const float* __restrict__ W_in,
                         const float* __restrict__ W_rec, const float* __restrict__ ns,
                         f16* __restrict__ edge_h, f16* __restrict__ W_inT,
                         f16* __restrict__ W_recT, float* __restrict__ nsmax,
                         float* __restrict__ nsmin)
{
    const int tid = blockIdx.x * 256 + threadIdx.x;     // grid 512*256 = 131072
    {
        const int i = tid >> 12, j = (tid >> 7) & 31;
        float v = edge[tid];
        if (i == j) v = 0.f;                            // off_diag baked in
        edge_h[tid] = (f16)v;
    }
    if (tid < 32768) {                                  // W_inT[c][k] = W_in[k][c]
        const int c = tid >> 8, k = tid & 255;
        W_inT[tid] = (f16)W_in[k * 128 + c];
    }
    if (tid < 32768) {                                  // W_recT[n][p] = W_rec[p][n]
        const int n = tid >> 7, p = tid & 127;
        W_recT[tid] = (f16)W_rec[p * 256 + n];
    }
    if (tid < 128) {
        float mx = -1e30f, mn = 1e30f;
        for (int i = 0; i < 32; ++i) {
            const float v = ns[i * 128 + tid];
            mx = fmaxf(mx, v); mn = fminf(mn, v);
        }
        nsmax[tid] = mx; nsmin[tid] = mn;
    }
}

// ---------------- xt = x @ W_in + b_in  (f16 out) ----------------
__global__ __launch_bounds__(256)
void agm_xt(const float* __restrict__ x, const f16* __restrict__ W_inT,
            const float* __restrict__ b_in, f16* __restrict__ xt)
{
    const int tid = threadIdx.x;
    const int w = tid >> 6, ln = tid & 63, g = ln >> 4, c15 = ln & 15;
    const int bt = blockIdx.x;                          // 16 batches per block
    const size_t brow = (size_t)(bt * 16 + c15) * 256;
    H8 A[8];
    #pragma unroll
    for (int ks = 0; ks < 8; ++ks) {
        const float4 pa = *(const float4*)(x + brow + ks * 32 + g * 8);
        const float4 pb = *(const float4*)(x + brow + ks * 32 + g * 8 + 4);
        A[ks].h = (f16x8){(f16)pa.x,(f16)pa.y,(f16)pa.z,(f16)pa.w,
                          (f16)pb.x,(f16)pb.y,(f16)pb.z,(f16)pb.w};
    }
    #pragma unroll
    for (int nt = 0; nt < 2; ++nt) {
        const int col = w * 32 + nt * 16 + c15;
        f32x4 d = {0,0,0,0};
        #pragma unroll
        for (int ks = 0; ks < 8; ++ks) {
            H8 b;
            b.u = *(const u32x4*)(W_inT + col * 256 + ks * 32 + g * 8);
            d = __builtin_amdgcn_mfma_f32_16x16x32_f16(A[ks].h, b.h, d, 0, 0, 0);
        }
        const float bc = b_in[col];
        #pragma unroll
        for (int r = 0; r < 4; ++r)
            xt[(size_t)(bt * 16 + g * 4 + r) * 128 + col] = (f16)(d[r] + bc);
    }
}

// ---------------- main: recurrence + fused out (16 waves, 15 batches) ----------
__global__ __launch_bounds__(1024, 4)
void agm_main(const f16* __restrict__ xto, const float* __restrict__ ns,
              const float* __restrict__ nsmax, const float* __restrict__ nsmin,
              const f16* __restrict__ edge_h, const f16* __restrict__ W_recT,
              const float* __restrict__ b_rec, const float* __restrict__ W_score,
              const float* __restrict__ b_score,
              float* __restrict__ out_rec, float* __restrict__ out_sc)
{
    __shared__ __align__(16) char smem[LDS_TOTAL];
    const int tid = threadIdx.x;
    const int w   = tid >> 6;          // wave 0..15; wave w<15 owns batch w
    const int ln  = tid & 63;
    const int g   = ln >> 4;
    const int c15 = ln & 15;
    const long bg0 = (long)blockIdx.x * NBATCH;

    int sig = 0;

    // ---- Phase A: st0 = ns + xt (scaled f16, max ~ 2^10) ----
    if (w < NBATCH) {
        long bgw = bg0 + w;
        if (bgw >= BTOT) bgw = BTOT - 1;
        const float xt0 = (float)xto[(size_t)bgw * 128 + ln];
        const float xt1 = (float)xto[(size_t)bgw * 128 + 64 + ln];
        float m = fmaxf(fmaxf(fabsf(nsmax[ln] + xt0),      fabsf(nsmin[ln] + xt0)),
                        fmaxf(fabsf(nsmax[ln + 64] + xt1), fabsf(nsmin[ln + 64] + xt1)));
        m = fmaxf(m, 1e-30f);
        m = fmaxf(m, __shfl_xor(m, 1));
        m = fmaxf(m, __shfl_xor(m, 2));
        m = fmaxf(m, __shfl_xor(m, 4));
        m = fmaxf(m, __shfl_xor(m, 8));
        m = fmaxf(m, __shfl_xor(m, 16));
        m = fmaxf(m, __shfl_xor(m, 32));
        sig = 10 - flog2(m);
        const float s0 = exp2i(sig);
        #pragma unroll 4
        for (int i = 0; i < 32; ++i) {
            *(f16*)(smem + ST(w) + i*ROWB + ln*2) =
                (f16)((ns[i*128 + ln] + xt0) * s0);
            *(f16*)(smem + ST(w) + i*ROWB + (ln + 64)*2) =
                (f16)((ns[i*128 + 64 + ln] + xt1) * s0);
        }
    }
    __syncthreads();

    // ---- 3 recurrence steps ----
    for (int t = 0; t < 3; ++t) {
        if (t < 2) {
            const int bb = c15 < NBATCH ? c15 : NBATCH - 1;
            #pragma unroll
            for (int ii = 0; ii < 2; ++ii) {
                const int i = w * 2 + ii;
                H8 Bf[4];
                #pragma unroll
                for (int ks = 0; ks < 4; ++ks)
                    Bf[ks].u = *(const u32x4*)(smem + ST(bb) + i*ROWB + (ks*32 + g*8)*2);
                f32x4 d0 = {0,0,0,0}, d1 = {0,0,0,0};
                #pragma unroll
                for (int ks = 0; ks < 4; ++ks) {
                    H8 A0, A1;
                    A0.u = *(const u32x4*)(edge_h + ((i*32 + c15)*128 + ks*32 + g*8));
                    A1.u = *(const u32x4*)(edge_h + ((i*32 + c15)*128 + 2048 + ks*32 + g*8));
                    if (i == c15)      A0.u = (u32x4){0,0,0,0};
                    if (i == 16 + c15) A1.u = (u32x4){0,0,0,0};
                    d0 = __builtin_amdgcn_mfma_f32_16x16x32_f16(A0.h, Bf[ks].h, d0, 0, 0, 0);
                    d1 = __builtin_amdgcn_mfma_f32_16x16x32_f16(A1.h, Bf[ks].h, d1, 0, 0, 0);
                }
                if (c15 < NBATCH) {
                    char* scb = smem + SC(c15) + i * 64;
                    H4 p0, p1;
                    #pragma unroll
                    for (int r = 0; r < 4; ++r) {
                        p0.h[r] = (f16)(d0[r] * 0x1p-8f);
                        p1.h[r] = (f16)(d1[r] * 0x1p-8f);
                    }
                    *(u32x2*)(scb + g*8)      = p0.u;
                    *(u32x2*)(scb + 32 + g*8) = p1.u;
                }
            }
        } else if (w == 15) {                            // t==2: only i = 31
            const int i = 31;
            const int bb = c15 < NBATCH ? c15 : NBATCH - 1;
            H8 Bf[4];
            #pragma unroll
            for (int ks = 0; ks < 4; ++ks)
                Bf[ks].u = *(const u32x4*)(smem + ST(bb) + i*ROWB + (ks*32 + g*8)*2);
            f32x4 d0 = {0,0,0,0}, d1 = {0,0,0,0};
            #pragma unroll
            for (int ks = 0; ks < 4; ++ks) {
                H8 A0, A1;
                A0.u = *(const u32x4*)(edge_h + ((i*32 + c15)*128 + ks*32 + g*8));
                A1.u = *(const u32x4*)(edge_h + ((i*32 + c15)*128 + 2048 + ks*32 + g*8));
                if (i == 16 + c15) A1.u = (u32x4){0,0,0,0};
                d0 = __builtin_amdgcn_mfma_f32_16x16x32_f16(A0.h, Bf[ks].h, d0, 0, 0, 0);
                d1 = __builtin_amdgcn_mfma_f32_16x16x32_f16(A1.h, Bf[ks].h, d1, 0, 0, 0);
            }
            if (c15 < NBATCH) {
                char* scb = smem + SC(c15) + i * 64;
                H4 p0, p1;
                #pragma unroll
                for (int r = 0; r < 4; ++r) {
                    p0.h[r] = (f16)(d0[r] * 0x1p-8f);
                    p1.h[r] = (f16)(d1[r] * 0x1p-8f);
                }
                *(u32x2*)(scb + g*8)      = p0.u;
                *(u32x2*)(scb + 32 + g*8) = p1.u;
            }
        }
        __syncthreads();

        // ---- part2: wave w updates batch w.  ge precomputed from bound ----
        if (w < NBATCH) {
            const int bb = w;
            char* scb = smem + SC(bb);
            if (t < 2) {
                H8 alo, ahi;
                alo.u = *(const u32x4*)(scb + c15*64 + g*16);          // S[i=c15][j]
                ahi.u = *(const u32x4*)(scb + 1024 + c15*64 + g*16);   // S[i=16+c15][j]
                // bound: max_i sum_j |S[i][j]| * max|st| (<= 2^11 by construction)
                float rs0 = 0.f, rs1 = 0.f;
                #pragma unroll
                for (int r = 0; r < 8; ++r) {
                    rs0 += fabsf((float)alo.h[r]);
                    rs1 += fabsf((float)ahi.h[r]);
                }
                rs0 += __shfl_xor(rs0, 16);  rs0 += __shfl_xor(rs0, 32);
                rs1 += __shfl_xor(rs1, 16);  rs1 += __shfl_xor(rs1, 32);
                float rmax = fmaxf(fmaxf(rs0, rs1), 1e-10f);
                rmax = fmaxf(rmax, __shfl_xor(rmax, 1));
                rmax = fmaxf(rmax, __shfl_xor(rmax, 2));
                rmax = fmaxf(rmax, __shfl_xor(rmax, 4));
                rmax = fmaxf(rmax, __shfl_xor(rmax, 8));
                int ge = 9 - flog2(rmax * 2048.0f);
                if (ge > 60) ge = 60;
                if (ge < -60) ge = -60;
                sig = 2 * sig - 8 + ge;
                const float gs = exp2i(ge);
                #pragma unroll
                for (int pt = 0; pt < 8; ++pt) {
                    H8 bf;
                    #pragma unroll
                    for (int jj = 0; jj < 8; ++jj)
                        bf.h[jj] = *(const f16*)(smem + ST(bb) + (g*8 + jj)*ROWB
                                                 + (pt*16 + c15)*2);
                    const f32x4 z = {0,0,0,0};
                    f32x4 dlo = __builtin_amdgcn_mfma_f32_16x16x32_f16(alo.h, bf.h, z, 0, 0, 0);
                    f32x4 dhi = __builtin_amdgcn_mfma_f32_16x16x32_f16(ahi.h, bf.h, z, 0, 0, 0);
                    const int p = pt*16 + c15;
                    #pragma unroll
                    for (int r = 0; r < 4; ++r) {
                        const int il = g*4 + r, ih = il + 16;
                        *(f16*)(smem + ST(bb) + il*ROWB + p*2) =
                            (f16)(fmaxf(dlo[r], 0.f) * gs);
                        *(f16*)(smem + ST(bb) + ih*ROWB + p*2) =
                            (f16)(fmaxf(dhi[r], 0.f) * gs);
                    }
                }
            } else {    // t==2: only hi i-tile; o31 row -> score LDS + sig -> LDS
                H8 ahi;
                ahi.u = *(const u32x4*)(scb + 1024 + c15*64 + g*16);
                float rs1 = 0.f;
                #pragma unroll
                for (int r = 0; r < 8; ++r) rs1 += fabsf((float)ahi.h[r]);
                rs1 += __shfl_xor(rs1, 16);  rs1 += __shfl_xor(rs1, 32);
                float rmax = fmaxf(rs1, 1e-10f);
                rmax = fmaxf(rmax, __shfl_xor(rmax, 1));
                rmax = fmaxf(rmax, __shfl_xor(rmax, 2));
                rmax = fmaxf(rmax, __shfl_xor(rmax, 4));
                rmax = fmaxf(rmax, __shfl_xor(rmax, 8));
                int ge = 9 - flog2(rmax * 2048.0f);
                if (ge > 60) ge = 60;
                if (ge < -60) ge = -60;
                sig = 2 * sig - 8 + ge;
                const float gs = exp2i(ge);
                #pragma unroll
                for (int pt = 0; pt < 8; ++pt) {
                    H8 bf;
                    #pragma unroll
                    for (int jj = 0; jj < 8; ++jj)
                        bf.h[jj] = *(const f16*)(smem + ST(bb) + (g*8 + jj)*ROWB
                                                 + (pt*16 + c15)*2);
                    const f32x4 z = {0,0,0,0};
                    f32x4 dhi = __builtin_amdgcn_mfma_f32_16x16x32_f16(ahi.h, bf.h, z, 0, 0, 0);
                    if (g == 3)                          // D row 31 = g3, r3
                        *(f16*)(scb + (pt*16 + c15)*2) =
                            (f16)(fmaxf(dhi[3], 0.f) * gs);   // o31 row over S[0..1]
                }
                if (ln == 0) ((int*)(smem + SIGF_OFF))[bb] = sig;
            }
        }
        __syncthreads();
    }

    // ---- fused out: out_rec = o31@W_rec*2^-sig + b_rec ; score ----
    {
        const int* sigf = (const int*)(smem + SIGF_OFF);
        const int bbx = c15 < NBATCH ? c15 : NBATCH - 1;
        H8 A[4];
        #pragma unroll
        for (int ks = 0; ks < 4; ++ks)
            A[ks].u = *(const u32x4*)(smem + SC(bbx) + (ks*32 + g*8)*2);
        float dsc[4];
        #pragma unroll
        for (int r = 0; r < 4; ++r) {
            const int batch = g*4 + r;
            int e = -(batch < NBATCH ? sigf[batch] : 0);
            if (e > 126) e = 126; if (e < -126) e = -126;
            dsc[r] = exp2i(e);
        }
        {
            const int col = w * 16 + c15;                // 16 waves x 16 cols = 256
            f32x4 d = {0,0,0,0};
            #pragma unroll
            for (int ks = 0; ks < 4; ++ks) {
                H8 b;
                b.u = *(const u32x4*)(W_recT + col*128 + ks*32 + g*8);
                d = __builtin_amdgcn_mfma_f32_16x16x32_f16(A[ks].h, b.h, d, 0, 0, 0);
            }
            const float bc = b_rec[col];
            #pragma unroll
            for (int r = 0; r < 4; ++r) {
                const int batch = g*4 + r;
                if (batch < NBATCH && bg0 + batch < BTOT)
                    out_rec[(bg0 + batch)*256 + col] = d[r]*dsc[r] + bc;
            }
        }
        if (w < NBATCH && bg0 + w < BTOT) {
            const char* ob = smem + SC(w);
            float v = (float)(*(const f16*)(ob + ln*2)) * W_score[ln]
                    + (float)(*(const f16*)(ob + (ln + 64)*2)) * W_score[ln + 64];
            v += __shfl_xor(v, 1);
            v += __shfl_xor(v, 2);
            v += __shfl_xor(v, 4);
            v += __shfl_xor(v, 8);
            v += __shfl_xor(v, 16);
            v += __shfl_xor(v, 32);
            int e = -sig;
            if (e > 126) e = 126; if (e < -126) e = -126;
            if (ln == 0) out_sc[bg0 + w] = v * exp2i(e) + b_score[0];
        }
    }
}

// ---------------- fallback: round-1 fp32 kernel (only if ws too small) ----------
__global__ __launch_bounds__(256, 2)
void agm_fb(const float* __restrict__ x, const float* __restrict__ W_in,
            const float* __restrict__ b_in, const float* __restrict__ ns,
            const float* __restrict__ edge, const float* __restrict__ W_rec,
            const float* __restrict__ b_rec, const float* __restrict__ W_score,
            const float* __restrict__ b_score, float* __restrict__ out_rec,
            float* __restrict__ out_sc)
{
    __shared__ float st[4][32][128];
    const int t = threadIdx.x;
    const int b = __builtin_amdgcn_readfirstlane(t >> 6);
    const int ln = t & 63;
    const long bg = (long)blockIdx.x * 4 + b;
    {
        const float* xb = x + bg * 256;
        float a0 = b_in[ln], a1 = b_in[ln + 64];
        for (int k = 0; k < 256; k += 4) {
            const float4 xv = *(const float4*)(xb + k);
            a0 += xv.x * W_in[(k+0)*128 + ln];  a1 += xv.x * W_in[(k+0)*128 + 64 + ln];
            a0 += xv.y * W_in[(k+1)*128 + ln];  a1 += xv.y * W_in[(k+1)*128 + 64 + ln];
            a0 += xv.z * W_in[(k+2)*128 + ln];  a1 += xv.z * W_in[(k+2)*128 + 64 + ln];
            a0 += xv.w * W_in[(k+3)*128 + ln];  a1 += xv.w * W_in[(k+3)*128 + 64 + ln];
        }
        for (int i = 0; i < 32; ++i) {
            st[b][i][ln]      = ns[i*128 + ln]      + a0;
            st[b][i][ln + 64] = ns[i*128 + 64 + ln] + a1;
        }
    }
    __syncthreads();
    const int h = ln >> 5, q4 = ln & 31;
    for (int step = 0; step < 2; ++step) {
        float acc0[32], acc1[32];
        #pragma unroll
        for (int i = 0; i < 32; ++i) { acc0[i] = 0.f; acc1[i] = 0.f; }
        for (int j = 0; j < 32; ++j) {
            const float s0 = st[b][j][ln], s1 = st[b][j][ln + 64];
            #pragma unroll
            for (int m = 0; m < 16; ++m) {
                const int i = 2*m + h;
                const float4 ev = *(const float4*)(edge + (((size_t)(i*32 + j)) << 7) + (q4 << 2));
                const float4 sv = *(const float4*)(&st[b][i][q4 << 2]);
                float s = ev.x*sv.x + ev.y*sv.y + ev.z*sv.z + ev.w*sv.w;
                s += __shfl_xor(s, 1); s += __shfl_xor(s, 2); s += __shfl_xor(s, 4);
                s += __shfl_xor(s, 8); s += __shfl_xor(s, 16);
                float c0 = __shfl(s, 0), c1 = __shfl(s, 32);
                if (2*m == j) c0 = 0.f;
                if (2*m + 1 == j) c1 = 0.f;
                acc0[2*m] += c0*s0; acc1[2*m] += c0*s1;
                acc0[2*m+1] += c1*s0; acc1[2*m+1] += c1*s1;
            }
            __syncthreads();
        }
        #pragma unroll
        for (int i = 0; i < 32; ++i) {
            st[b][i][ln]      = fmaxf(acc0[i], 0.f);
            st[b][i][ln + 64] = fmaxf(acc1[i], 0.f);
        }
        __syncthreads();
    }
    {
        float o0 = 0.f, o1 = 0.f;
        #pragma unroll
        for (int m = 0; m < 16; ++m) {
            const int jj = 2*m + h;
            const float4 ev = *(const float4*)(edge + (((size_t)(31*32 + jj)) << 7) + (q4 << 2));
            const float4 sv = *(const float4*)(&st[b][31][q4 << 2]);
            float s = ev.x*sv.x + ev.y*sv.y + ev.z*sv.z + ev.w*sv.w;
            s += __shfl_xor(s, 1); s += __shfl_xor(s, 2); s += __shfl_xor(s, 4);
            s += __shfl_xor(s, 8); s += __shfl_xor(s, 16);
            float c0 = __shfl(s, 0), c1 = __shfl(s, 32);
            if (2*m == 31) c0 = 0.f;
            if (2*m + 1 == 31) c1 = 0.f;
            o0 += c0*st[b][2*m][ln] + c1*st[b][2*m+1][ln];
            o1 += c0*st[b][2*m][ln+64] + c1*st[b][2*m+1][ln+64];
        }
        __syncthreads();
        st[b][0][ln] = fmaxf(o0, 0.f);
        st[b][0][ln + 64] = fmaxf(o1, 0.f);
    }
    __syncthreads();
    {
        const float* ob = &st[b][0][0];
        float r0 = b_rec[ln], r1 = b_rec[ln+64], r2 = b_rec[ln+128], r3 = b_rec[ln+192];
        for (int p = 0; p < 128; ++p) {
            const float ov = ob[p];
            r0 += ov * W_rec[p*256 + ln];       r1 += ov * W_rec[p*256 + 64 + ln];
            r2 += ov * W_rec[p*256 + 128 + ln]; r3 += ov * W_rec[p*256 + 192 + ln];
        }
        float* orow = out_rec + bg * 256;
        orow[ln] = r0; orow[ln+64] = r1; orow[ln+128] = r2; orow[ln+192] = r3;
        float s = ob[ln]*W_score[ln] + ob[ln+64]*W_score[ln+64];
        s += __shfl_xor(s, 32); s += __shfl_xor(s, 16); s += __shfl_xor(s, 8);
        s += __shfl_xor(s, 4);  s += __shfl_xor(s, 2);  s += __shfl_xor(s, 1);
        if (ln == 0) out_sc[bg] = s + b_score[0];
    }
}

extern "C" void kernel_launch(void* const* d_in, const int* in_sizes, int n_in,
                              void* d_out, int out_size, void* d_ws, size_t ws_size,
                              hipStream_t stream) {
    const float* x     = (const float*)d_in[0];
    const float* W_in  = (const float*)d_in[1];
    const float* bin   = (const float*)d_in[2];
    const float* ns    = (const float*)d_in[3];
    const float* edge  = (const float*)d_in[4];
    const float* W_rec = (const float*)d_in[5];
    const float* brec  = (const float*)d_in[6];
    const float* W_sc  = (const float*)d_in[7];
    const float* b_sc  = (const float*)d_in[8];
    (void)n_in;

    const int B = in_sizes[0] / 256;               // 16384
    float* out = (float*)d_out;
    float* outsc = out + (size_t)B * 256;

    if (ws_size < (size_t)WS_NEED) {
        agm_fb<<<dim3(B / 4), dim3(256), 0, stream>>>(
            x, W_in, bin, ns, edge, W_rec, brec, W_sc, b_sc, out, outsc);
        return;
    }

    char* ws = (char*)d_ws;
    f16*   edge_h = (f16*)(ws + WS_EH);
    f16*   W_inT  = (f16*)(ws + WS_WINT);
    f16*   W_recT = (f16*)(ws + WS_WRECT);
    float* nsmax  = (float*)(ws + WS_NSMX);
    float* nsmin  = (float*)(ws + WS_NSMN);
    f16*   xto    = (f16*)(ws + WS_XT);

    agm_conv<<<dim3(512), dim3(256), 0, stream>>>(edge, W_in, W_rec, ns,
                                                  edge_h, W_inT, W_recT, nsmax, nsmin);
    agm_xt<<<dim3(B / 16), dim3(256), 0, stream>>>(x, W_inT, bin, xto);
    const int nblk = (B + NBATCH - 1) / NBATCH;    // 1093
    agm_main<<<dim3(nblk), dim3(1024), 0, stream>>>(xto, ns, nsmax, nsmin, edge_h,
                                                    W_recT, brec, W_sc, b_sc,
                                                    out, outsc);
}

// Round 20
// 155.812 us; speedup vs baseline: 1.2139x; 1.2139x over previous
//
#include <hip/hip_runtime.h>
#include <cstdint>

// AGMBrain: B=16384, INPUT_DIM=256, N=32 neurons, D=128, 3 steps.
// Round 20: NBATCH=16, grid=1024 = exactly 4 blocks/CU (no tail round).
//   r19 falsified "time ~ block count": per-batch serial work + round
//   granularity dominate (1093 blocks = 4.27 rounds, 69-block tail).
//   16 batches/block: 1024 blocks = 4.00 full rounds, part1 N-util 16/16.
//   LDS forced tight: ROWB=256, STB=8192, SC_BS=2048, sig inside score
//   block (+256B, dead at t==2) -> LDS = 163840 B exactly (the 160KiB cap).
//   Re-admits r14-era bank conflicts (batch stride = 0 mod 128) -- r16
//   proved conflicts are fully hidden at this occupancy (40% reduction
//   changed time 0.0us). Numerics identical per batch -> absmax must stay
//   exactly 1.099512e12.
//   pipeline: agm_conv -> agm_xt -> agm_main   (ws 4.65MB layout unchanged)

#define BTOT 16384
#define NBATCH 16
#define ROWB 256                 // bytes per state row (128 f16, no pad)
#define STB  8192                // bytes per batch
#define ST(b) ((b) * STB)
#define SC_BASE 131072           // 16*8192
#define SC_BS 2048
#define SC(b) (SC_BASE + (b) * SC_BS)  // scores S[i][j] f16, 64B/row; o31+sig at t==2
#define LDS_TOTAL 163840         // == 160KiB cap, 1 block/CU

#define WS_EH    0
#define WS_WINT  262144
#define WS_WRECT 327680
#define WS_NSMX  393216
#define WS_NSMN  393728
#define WS_XT    394240
#define WS_NEED  4654080

typedef _Float16 f16;
typedef _Float16 f16x8 __attribute__((ext_vector_type(8)));
typedef float f32x4 __attribute__((ext_vector_type(4)));
typedef unsigned int u32x4 __attribute__((ext_vector_type(4)));
typedef unsigned int u32x2 __attribute__((ext_vector_type(2)));

union H8 { u32x4 u; f16x8 h; };
union H4 { u32x2 u; f16 h[4]; };

__device__ __forceinline__ float exp2i(int e) {      // 2^e, e in [-126,127]
    return __uint_as_float((unsigned)(e + 127) << 23);
}
__device__ __forceinline__ int flog2(float m) {      // floor(log2 m), m>0 normal
    return (int)((__float_as_uint(m) >> 23) & 0xFF) - 127;
}

// ---------------- conv: edge->f16(diag0), W_inT, W_recT, ns col extremes ----
__global__ void agm_conv(const float* __restrict__ edge, const float* __restrict__ W_in,
                         const float* __restrict__ W_rec, const float* __restrict__ ns,
                         f16* __restrict__ edge_h, f16* __restrict__ W_inT,
                         f16* __restrict__ W_recT, float* __restrict__ nsmax,
                         float* __restrict__ nsmin)
{
    const int tid = blockIdx.x * 256 + threadIdx.x;     // grid 512*256 = 131072
    {
        const int i = tid >> 12, j = (tid >> 7) & 31;
        float v = edge[tid];
        if (i == j) v = 0.f;                            // off_diag baked in
        edge_h[tid] = (f16)v;
    }
    if (tid < 32768) {                                  // W_inT[c][k] = W_in[k][c]
        const int c = tid >> 8, k = tid & 255;
        W_inT[tid] = (f16)W_in[k * 128 + c];
    }
    if (tid < 32768) {                                  // W_recT[n][p] = W_rec[p][n]
        const int n = tid >> 7, p = tid & 127;
        W_recT[tid] = (f16)W_rec[p * 256 + n];
    }
    if (tid < 128) {
        float mx = -1e30f, mn = 1e30f;
        for (int i = 0; i < 32; ++i) {
            const float v = ns[i * 128 + tid];
            mx = fmaxf(mx, v); mn = fminf(mn, v);
        }
        nsmax[tid] = mx; nsmin[tid] = mn;
    }
}

// ---------------- xt = x @ W_in + b_in  (f16 out) ----------------
__global__ __launch_bounds__(256)
void agm_xt(const float* __restrict__ x, const f16* __restrict__ W_inT,
            const float* __restrict__ b_in, f16* __restrict__ xt)
{
    const int tid = threadIdx.x;
    const int w = tid >> 6, ln = tid & 63, g = ln >> 4, c15 = ln & 15;
    const int bt = blockIdx.x;                          // 16 batches per block
    const size_t brow = (size_t)(bt * 16 + c15) * 256;
    H8 A[8];
    #pragma unroll
    for (int ks = 0; ks < 8; ++ks) {
        const float4 pa = *(const float4*)(x + brow + ks * 32 + g * 8);
        const float4 pb = *(const float4*)(x + brow + ks * 32 + g * 8 + 4);
        A[ks].h = (f16x8){(f16)pa.x,(f16)pa.y,(f16)pa.z,(f16)pa.w,
                          (f16)pb.x,(f16)pb.y,(f16)pb.z,(f16)pb.w};
    }
    #pragma unroll
    for (int nt = 0; nt < 2; ++nt) {
        const int col = w * 32 + nt * 16 + c15;
        f32x4 d = {0,0,0,0};
        #pragma unroll
        for (int ks = 0; ks < 8; ++ks) {
            H8 b;
            b.u = *(const u32x4*)(W_inT + col * 256 + ks * 32 + g * 8);
            d = __builtin_amdgcn_mfma_f32_16x16x32_f16(A[ks].h, b.h, d, 0, 0, 0);
        }
        const float bc = b_in[col];
        #pragma unroll
        for (int r = 0; r < 4; ++r)
            xt[(size_t)(bt * 16 + g * 4 + r) * 128 + col] = (f16)(d[r] + bc);
    }
}

// ---------------- main: recurrence + fused out (16 waves, 16 batches) ----------
__global__ __launch_bounds__(1024, 4)
void agm_main(const f16* __restrict__ xto, const float* __restrict__ ns,
              const float* __restrict__ nsmax, const float* __restrict__ nsmin,
              const f16* __restrict__ edge_h, const f16* __restrict__ W_recT,
              const float* __restrict__ b_rec, const float* __restrict__ W_score,
              const float* __restrict__ b_score,
              float* __restrict__ out_rec, float* __restrict__ out_sc)
{
    __shared__ __align__(16) char smem[LDS_TOTAL];
    const int tid = threadIdx.x;
    const int w   = tid >> 6;          // wave 0..15; wave w owns batch w
    const int ln  = tid & 63;
    const int g   = ln >> 4;
    const int c15 = ln & 15;
    const long bg0 = (long)blockIdx.x * NBATCH;

    int sig = 0;

    // ---- Phase A: st0 = ns + xt (scaled f16, max ~ 2^10) ----
    {
        const long bgw = bg0 + w;                       // B = 1024*16 exactly
        const float xt0 = (float)xto[(size_t)bgw * 128 + ln];
        const float xt1 = (float)xto[(size_t)bgw * 128 + 64 + ln];
        float m = fmaxf(fmaxf(fabsf(nsmax[ln] + xt0),      fabsf(nsmin[ln] + xt0)),
                        fmaxf(fabsf(nsmax[ln + 64] + xt1), fabsf(nsmin[ln + 64] + xt1)));
        m = fmaxf(m, 1e-30f);
        m = fmaxf(m, __shfl_xor(m, 1));
        m = fmaxf(m, __shfl_xor(m, 2));
        m = fmaxf(m, __shfl_xor(m, 4));
        m = fmaxf(m, __shfl_xor(m, 8));
        m = fmaxf(m, __shfl_xor(m, 16));
        m = fmaxf(m, __shfl_xor(m, 32));
        sig = 10 - flog2(m);
        const float s0 = exp2i(sig);
        #pragma unroll 4
        for (int i = 0; i < 32; ++i) {
            *(f16*)(smem + ST(w) + i*ROWB + ln*2) =
                (f16)((ns[i*128 + ln] + xt0) * s0);
            *(f16*)(smem + ST(w) + i*ROWB + (ln + 64)*2) =
                (f16)((ns[i*128 + 64 + ln] + xt1) * s0);
        }
    }
    __syncthreads();

    // ---- 3 recurrence steps ----
    for (int t = 0; t < 3; ++t) {
        if (t < 2) {
            const int bb = c15;                         // 16 batch columns
            #pragma unroll
            for (int ii = 0; ii < 2; ++ii) {
                const int i = w * 2 + ii;
                H8 Bf[4];
                #pragma unroll
                for (int ks = 0; ks < 4; ++ks)
                    Bf[ks].u = *(const u32x4*)(smem + ST(bb) + i*ROWB + (ks*32 + g*8)*2);
                f32x4 d0 = {0,0,0,0}, d1 = {0,0,0,0};
                #pragma unroll
                for (int ks = 0; ks < 4; ++ks) {
                    H8 A0, A1;
                    A0.u = *(const u32x4*)(edge_h + ((i*32 + c15)*128 + ks*32 + g*8));
                    A1.u = *(const u32x4*)(edge_h + ((i*32 + c15)*128 + 2048 + ks*32 + g*8));
                    if (i == c15)      A0.u = (u32x4){0,0,0,0};
                    if (i == 16 + c15) A1.u = (u32x4){0,0,0,0};
                    d0 = __builtin_amdgcn_mfma_f32_16x16x32_f16(A0.h, Bf[ks].h, d0, 0, 0, 0);
                    d1 = __builtin_amdgcn_mfma_f32_16x16x32_f16(A1.h, Bf[ks].h, d1, 0, 0, 0);
                }
                {
                    char* scb = smem + SC(c15) + i * 64;
                    H4 p0, p1;
                    #pragma unroll
                    for (int r = 0; r < 4; ++r) {
                        p0.h[r] = (f16)(d0[r] * 0x1p-8f);
                        p1.h[r] = (f16)(d1[r] * 0x1p-8f);
                    }
                    *(u32x2*)(scb + g*8)      = p0.u;
                    *(u32x2*)(scb + 32 + g*8) = p1.u;
                }
            }
        } else if (w == 0) {                            // t==2: only i = 31
            const int i = 31;
            const int bb = c15;
            H8 Bf[4];
            #pragma unroll
            for (int ks = 0; ks < 4; ++ks)
                Bf[ks].u = *(const u32x4*)(smem + ST(bb) + i*ROWB + (ks*32 + g*8)*2);
            f32x4 d0 = {0,0,0,0}, d1 = {0,0,0,0};
            #pragma unroll
            for (int ks = 0; ks < 4; ++ks) {
                H8 A0, A1;
                A0.u = *(const u32x4*)(edge_h + ((i*32 + c15)*128 + ks*32 + g*8));
                A1.u = *(const u32x4*)(edge_h + ((i*32 + c15)*128 + 2048 + ks*32 + g*8));
                if (i == 16 + c15) A1.u = (u32x4){0,0,0,0};
                d0 = __builtin_amdgcn_mfma_f32_16x16x32_f16(A0.h, Bf[ks].h, d0, 0, 0, 0);
                d1 = __builtin_amdgcn_mfma_f32_16x16x32_f16(A1.h, Bf[ks].h, d1, 0, 0, 0);
            }
            {
                char* scb = smem + SC(c15) + i * 64;
                H4 p0, p1;
                #pragma unroll
                for (int r = 0; r < 4; ++r) {
                    p0.h[r] = (f16)(d0[r] * 0x1p-8f);
                    p1.h[r] = (f16)(d1[r] * 0x1p-8f);
                }
                *(u32x2*)(scb + g*8)      = p0.u;
                *(u32x2*)(scb + 32 + g*8) = p1.u;
            }
        }
        __syncthreads();

        // ---- part2: wave w updates batch w.  ge precomputed from bound ----
        {
            const int bb = w;
            char* scb = smem + SC(bb);
            if (t < 2) {
                H8 alo, ahi;
                alo.u = *(const u32x4*)(scb + c15*64 + g*16);          // S[i=c15][j]
                ahi.u = *(const u32x4*)(scb + 1024 + c15*64 + g*16);   // S[i=16+c15][j]
                // bound: max_i sum_j |S[i][j]| * max|st| (<= 2^11 by construction)
                float rs0 = 0.f, rs1 = 0.f;
                #pragma unroll
                for (int r = 0; r < 8; ++r) {
                    rs0 += fabsf((float)alo.h[r]);
                    rs1 += fabsf((float)ahi.h[r]);
                }
                rs0 += __shfl_xor(rs0, 16);  rs0 += __shfl_xor(rs0, 32);
                rs1 += __shfl_xor(rs1, 16);  rs1 += __shfl_xor(rs1, 32);
                float rmax = fmaxf(fmaxf(rs0, rs1), 1e-10f);
                rmax = fmaxf(rmax, __shfl_xor(rmax, 1));
                rmax = fmaxf(rmax, __shfl_xor(rmax, 2));
                rmax = fmaxf(rmax, __shfl_xor(rmax, 4));
                rmax = fmaxf(rmax, __shfl_xor(rmax, 8));
                int ge = 9 - flog2(rmax * 2048.0f);
                if (ge > 60) ge = 60;
                if (ge < -60) ge = -60;
                sig = 2 * sig - 8 + ge;
                const float gs = exp2i(ge);
                #pragma unroll
                for (int pt = 0; pt < 8; ++pt) {
                    H8 bf;
                    #pragma unroll
                    for (int jj = 0; jj < 8; ++jj)
                        bf.h[jj] = *(const f16*)(smem + ST(bb) + (g*8 + jj)*ROWB
                                                 + (pt*16 + c15)*2);
                    const f32x4 z = {0,0,0,0};
                    f32x4 dlo = __builtin_amdgcn_mfma_f32_16x16x32_f16(alo.h, bf.h, z, 0, 0, 0);
                    f32x4 dhi = __builtin_amdgcn_mfma_f32_16x16x32_f16(ahi.h, bf.h, z, 0, 0, 0);
                    const int p = pt*16 + c15;
                    #pragma unroll
                    for (int r = 0; r < 4; ++r) {
                        const int il = g*4 + r, ih = il + 16;
                        *(f16*)(smem + ST(bb) + il*ROWB + p*2) =
                            (f16)(fmaxf(dlo[r], 0.f) * gs);
                        *(f16*)(smem + ST(bb) + ih*ROWB + p*2) =
                            (f16)(fmaxf(dhi[r], 0.f) * gs);
                    }
                }
            } else {    // t==2: only hi i-tile; o31 row -> scb[0..255], sig -> scb+256
                H8 ahi;
                ahi.u = *(const u32x4*)(scb + 1024 + c15*64 + g*16);
                float rs1 = 0.f;
                #pragma unroll
                for (int r = 0; r < 8; ++r) rs1 += fabsf((float)ahi.h[r]);
                rs1 += __shfl_xor(rs1, 16);  rs1 += __shfl_xor(rs1, 32);
                float rmax = fmaxf(rs1, 1e-10f);
                rmax = fmaxf(rmax, __shfl_xor(rmax, 1));
                rmax = fmaxf(rmax, __shfl_xor(rmax, 2));
                rmax = fmaxf(rmax, __shfl_xor(rmax, 4));
                rmax = fmaxf(rmax, __shfl_xor(rmax, 8));
                int ge = 9 - flog2(rmax * 2048.0f);
                if (ge > 60) ge = 60;
                if (ge < -60) ge = -60;
                sig = 2 * sig - 8 + ge;
                const float gs = exp2i(ge);
                #pragma unroll
                for (int pt = 0; pt < 8; ++pt) {
                    H8 bf;
                    #pragma unroll
                    for (int jj = 0; jj < 8; ++jj)
                        bf.h[jj] = *(const f16*)(smem + ST(bb) + (g*8 + jj)*ROWB
                                                 + (pt*16 + c15)*2);
                    const f32x4 z = {0,0,0,0};
                    f32x4 dhi = __builtin_amdgcn_mfma_f32_16x16x32_f16(ahi.h, bf.h, z, 0, 0, 0);
                    if (g == 3)                          // D row 31 = g3, r3
                        *(f16*)(scb + (pt*16 + c15)*2) =
                            (f16)(fmaxf(dhi[3], 0.f) * gs);   // o31 over dead S rows 0-3
                }
                if (ln == 0) *(int*)(scb + 256) = sig;   // dead S row 4 region
            }
        }
        __syncthreads();
    }

    // ---- fused out: out_rec = o31@W_rec*2^-sig + b_rec ; score ----
    {
        H8 A[4];
        #pragma unroll
        for (int ks = 0; ks < 4; ++ks)
            A[ks].u = *(const u32x4*)(smem + SC(c15) + (ks*32 + g*8)*2);
        float dsc[4];
        #pragma unroll
        for (int r = 0; r < 4; ++r) {
            const int batch = g*4 + r;
            int e = -*(const int*)(smem + SC(batch) + 256);
            if (e > 126) e = 126; if (e < -126) e = -126;
            dsc[r] = exp2i(e);
        }
        {
            const int col = w * 16 + c15;                // 16 waves x 16 cols = 256
            f32x4 d = {0,0,0,0};
            #pragma unroll
            for (int ks = 0; ks < 4; ++ks) {
                H8 b;
                b.u = *(const u32x4*)(W_recT + col*128 + ks*32 + g*8);
                d = __builtin_amdgcn_mfma_f32_16x16x32_f16(A[ks].h, b.h, d, 0, 0, 0);
            }
            const float bc = b_rec[col];
            #pragma unroll
            for (int r = 0; r < 4; ++r) {
                const int batch = g*4 + r;
                out_rec[(bg0 + batch)*256 + col] = d[r]*dsc[r] + bc;
            }
        }
        {
            const char* ob = smem + SC(w);
            float v = (float)(*(const f16*)(ob + ln*2)) * W_score[ln]
                    + (float)(*(const f16*)(ob + (ln + 64)*2)) * W_score[ln + 64];
            v += __shfl_xor(v, 1);
            v += __shfl_xor(v, 2);
            v += __shfl_xor(v, 4);
            v += __shfl_xor(v, 8);
            v += __shfl_xor(v, 16);
            v += __shfl_xor(v, 32);
            int e = -sig;
            if (e > 126) e = 126; if (e < -126) e = -126;
            if (ln == 0) out_sc[bg0 + w] = v * exp2i(e) + b_score[0];
        }
    }
}

// ---------------- fallback: round-1 fp32 kernel (only if ws too small) ----------
__global__ __launch_bounds__(256, 2)
void agm_fb(const float* __restrict__ x, const float* __restrict__ W_in,
            const float* __restrict__ b_in, const float* __restrict__ ns,
            const float* __restrict__ edge, const float* __restrict__ W_rec,
            const float* __restrict__ b_rec, const float* __restrict__ W_score,
            const float* __restrict__ b_score, float* __restrict__ out_rec,
            float* __restrict__ out_sc)
{
    __shared__ float st[4][32][128];
    const int t = threadIdx.x;
    const int b = __builtin_amdgcn_readfirstlane(t >> 6);
    const int ln = t & 63;
    const long bg = (long)blockIdx.x * 4 + b;
    {
        const float* xb = x + bg * 256;
        float a0 = b_in[ln], a1 = b_in[ln + 64];
        for (int k = 0; k < 256; k += 4) {
            const float4 xv = *(const float4*)(xb + k);
            a0 += xv.x * W_in[(k+0)*128 + ln];  a1 += xv.x * W_in[(k+0)*128 + 64 + ln];
            a0 += xv.y * W_in[(k+1)*128 + ln];  a1 += xv.y * W_in[(k+1)*128 + 64 + ln];
            a0 += xv.z * W_in[(k+2)*128 + ln];  a1 += xv.z * W_in[(k+2)*128 + 64 + ln];
            a0 += xv.w * W_in[(k+3)*128 + ln];  a1 += xv.w * W_in[(k+3)*128 + 64 + ln];
        }
        for (int i = 0; i < 32; ++i) {
            st[b][i][ln]      = ns[i*128 + ln]      + a0;
            st[b][i][ln + 64] = ns[i*128 + 64 + ln] + a1;
        }
    }
    __syncthreads();
    const int h = ln >> 5, q4 = ln & 31;
    for (int step = 0; step < 2; ++step) {
        float acc0[32], acc1[32];
        #pragma unroll
        for (int i = 0; i < 32; ++i) { acc0[i] = 0.f; acc1[i] = 0.f; }
        for (int j = 0; j < 32; ++j) {
            const float s0 = st[b][j][ln], s1 = st[b][j][ln + 64];
            #pragma unroll
            for (int m = 0; m < 16; ++m) {
                const int i = 2*m + h;
                const float4 ev = *(const float4*)(edge + (((size_t)(i*32 + j)) << 7) + (q4 << 2));
                const float4 sv = *(const float4*)(&st[b][i][q4 << 2]);
                float s = ev.x*sv.x + ev.y*sv.y + ev.z*sv.z + ev.w*sv.w;
                s += __shfl_xor(s, 1); s += __shfl_xor(s, 2); s += __shfl_xor(s, 4);
                s += __shfl_xor(s, 8); s += __shfl_xor(s, 16);
                float c0 = __shfl(s, 0), c1 = __shfl(s, 32);
                if (2*m == j) c0 = 0.f;
                if (2*m + 1 == j) c1 = 0.f;
                acc0[2*m] += c0*s0; acc1[2*m] += c0*s1;
                acc0[2*m+1] += c1*s0; acc1[2*m+1] += c1*s1;
            }
            __syncthreads();
        }
        #pragma unroll
        for (int i = 0; i < 32; ++i) {
            st[b][i][ln]      = fmaxf(acc0[i], 0.f);
            st[b][i][ln + 64] = fmaxf(acc1[i], 0.f);
        }
        __syncthreads();
    }
    {
        float o0 = 0.f, o1 = 0.f;
        #pragma unroll
        for (int m = 0; m < 16; ++m) {
            const int jj = 2*m + h;
            const float4 ev = *(const float4*)(edge + (((size_t)(31*32 + jj)) << 7) + (q4 << 2));
            const float4 sv = *(const float4*)(&st[b][31][q4 << 2]);
            float s = ev.x*sv.x + ev.y*sv.y + ev.z*sv.z + ev.w*sv.w;
            s += __shfl_xor(s, 1); s += __shfl_xor(s, 2); s += __shfl_xor(s, 4);
            s += __shfl_xor(s, 8); s += __shfl_xor(s, 16);
            float c0 = __shfl(s, 0), c1 = __shfl(s, 32);
            if (2*m == 31) c0 = 0.f;
            if (2*m + 1 == 31) c1 = 0.f;
            o0 += c0*st[b][2*m][ln] + c1*st[b][2*m+1][ln];
            o1 += c0*st[b][2*m][ln+64] + c1*st[b][2*m+1][ln+64];
        }
        __syncthreads();
        st[b][0][ln] = fmaxf(o0, 0.f);
        st[b][0][ln + 64] = fmaxf(o1, 0.f);
    }
    __syncthreads();
    {
        const float* ob = &st[b][0][0];
        float r0 = b_rec[ln], r1 = b_rec[ln+64], r2 = b_rec[ln+128], r3 = b_rec[ln+192];
        for (int p = 0; p < 128; ++p) {
            const float ov = ob[p];
            r0 += ov * W_rec[p*256 + ln];       r1 += ov * W_rec[p*256 + 64 + ln];
            r2 += ov * W_rec[p*256 + 128 + ln]; r3 += ov * W_rec[p*256 + 192 + ln];
        }
        float* orow = out_rec + bg * 256;
        orow[ln] = r0; orow[ln+64] = r1; orow[ln+128] = r2; orow[ln+192] = r3;
        float s = ob[ln]*W_score[ln] + ob[ln+64]*W_score[ln+64];
        s += __shfl_xor(s, 32); s += __shfl_xor(s, 16); s += __shfl_xor(s, 8);
        s += __shfl_xor(s, 4);  s += __shfl_xor(s, 2);  s += __shfl_xor(s, 1);
        if (ln == 0) out_sc[bg] = s + b_score[0];
    }
}

extern "C" void kernel_launch(void* const* d_in, const int* in_sizes, int n_in,
                              void* d_out, int out_size, void* d_ws, size_t ws_size,
                              hipStream_t stream) {
    const float* x     = (const float*)d_in[0];
    const float* W_in  = (const float*)d_in[1];
    const float* bin   = (const float*)d_in[2];
    const float* ns    = (const float*)d_in[3];
    const float* edge  = (const float*)d_in[4];
    const float* W_rec = (const float*)d_in[5];
    const float* brec  = (const float*)d_in[6];
    const float* W_sc  = (const float*)d_in[7];
    const float* b_sc  = (const float*)d_in[8];
    (void)n_in;

    const int B = in_sizes[0] / 256;               // 16384
    float* out = (float*)d_out;
    float* outsc = out + (size_t)B * 256;

    if (ws_size < (size_t)WS_NEED || (B % NBATCH) != 0) {
        agm_fb<<<dim3(B / 4), dim3(256), 0, stream>>>(
            x, W_in, bin, ns, edge, W_rec, brec, W_sc, b_sc, out, outsc);
        return;
    }

    char* ws = (char*)d_ws;
    f16*   edge_h = (f16*)(ws + WS_EH);
    f16*   W_inT  = (f16*)(ws + WS_WINT);
    f16*   W_recT = (f16*)(ws + WS_WRECT);
    float* nsmax  = (float*)(ws + WS_NSMX);
    float* nsmin  = (float*)(ws + WS_NSMN);
    f16*   xto    = (f16*)(ws + WS_XT);

    agm_conv<<<dim3(512), dim3(256), 0, stream>>>(edge, W_in, W_rec, ns,
                                                  edge_h, W_inT, W_recT, nsmax, nsmin);
    agm_xt<<<dim3(B / 16), dim3(256), 0, stream>>>(x, W_inT, bin, xto);
    const int nblk = B / NBATCH;                   // 1024 = exactly 4 blocks/CU
    agm_main<<<dim3(nblk), dim3(1024), 0, stream>>>(xto, ns, nsmax, nsmin, edge_h,
                                                    W_recT, brec, W_sc, b_sc,
                                                    out, outsc);
}